// Round 15
// baseline (96.385 us; speedup 1.0000x reference)
//
#include <hip/hip_runtime.h>
#include <math.h>

// P2V: out[b,dhw] = top2-margin over n of softmax_n( |s2| * exp(-|s1| * dist) )
// dist = |x|^2 + |g|^2 - 2 x.g
//
// Round 14 kernel, resubmitted (R14 bench was a container infra failure;
// never ran). R13 verified the component model (VALU-busy 29.6us == 29us
// prediction; LDS 20.5us) but occupancy collapsed (1024 blocks -> 25%) so
// LDS stopped hiding under VALU. Fix: SAME work split (2 outputs per
// ds_read_b128) at R10's grid: 2048 blocks, octet (8 lanes) serves outputs
// {dhwA, dhwA+32}, lane covers n = 8i+c (128 iters). Per-CU: 4096 ds_read
// (20.5us) overlapped under 29us VALU at ~50% occupancy -> ~31us.
// Bank check: 8 distinct float4 x 8-fold broadcast = all 32 banks, no
// conflict. R11 lesson: scalars only, no register arrays.
//
// Math (= R10): q = -c1|x|^2 + 2c1(x.g), c1=log2e*|s1|; u = 2^q; v = Ct*u,
//   Ct = |s2|*2^(-c1|g|^2); top-2 of v == top-2 of q (monotone).
//   fast (s2a<=1): e^v ~ PC0 + u*Q(u) (deg-4 minimax, Ct^k folded into Q);
//     S_true = 1024*PC0 + sum(Q(u)u);  num = exact exp2: e^{v0} - e^{v1}.
//   general: S = sum 2^(EC*2^q - Ls2); out = 2^(EC*u0-Ls2)(1-2^(EC(u1-u0)))/S.

#define LOG2E 1.44269504088896340736f
// deg-4 minimax (Chebyshev) coeffs for e^x on [0,1], abs err <= 2.8e-5
#define PC0 1.0000247f
#define PC1 0.9987113f
#define PC2 0.5099871f
#define PC3 0.1399751f
#define PC4 0.0695533f

__device__ __forceinline__ void omerge(float& t0, float& t1, float& S) {
    #pragma unroll
    for (int m = 1; m <= 4; m <<= 1) {       // 8-lane butterfly
        const float o0 = __shfl_xor(t0, m);
        const float o1 = __shfl_xor(t1, m);
        const float oS = __shfl_xor(S, m);
        t1 = fmaxf(fminf(t0, o0), fmaxf(t1, o1));
        t0 = fmaxf(t0, o0);
        S += oS;
    }
}

__global__ __launch_bounds__(256, 8) void p2v_kernel(
    const float* __restrict__ xyz,   // (B=4, C=3, N=1024)
    const float* __restrict__ grid,  // (C=3, 32768)
    const float* __restrict__ s1,
    const float* __restrict__ s2,
    float* __restrict__ out)         // (B=4, 32768)
{
    __shared__ float4 A[1024];       // 16 KB per-n table for this block's b

    const int tid  = threadIdx.x;
    const int b    = blockIdx.x >> 9;           // 512 blocks per b
    const int k    = blockIdx.x & 511;          // 64 outputs per block
    const int oct  = tid >> 3;                  // 32 octets
    const int c    = tid & 7;                   // n-chunk within octet
    const int dhwA = (k << 6) + oct;            // octet's output #1
    const int dhwB = dhwA + 32;                 // octet's output #2

    const float s1a = fabsf(s1[0]);
    const float s2a = fabsf(s2[0]);
    const float c1  = LOG2E * s1a;

    const float* xb = xyz + b * 3072;
    #pragma unroll
    for (int i = 0; i < 4; ++i) {
        const int n = tid + i * 256;
        const float x = xb[n], y = xb[1024 + n], z = xb[2048 + n];
        const float x2 = fmaf(x, x, fmaf(y, y, z * z));
        A[n] = make_float4(-c1 * x2, 2.f * c1 * x, 2.f * c1 * y, 2.f * c1 * z);
    }
    __syncthreads();

    const float gA0 = grid[dhwA], gA1 = grid[32768 + dhwA], gA2 = grid[65536 + dhwA];
    const float gB0 = grid[dhwB], gB1 = grid[32768 + dhwB], gB2 = grid[65536 + dhwB];
    const float CtA = s2a * __builtin_amdgcn_exp2f(
        -c1 * fmaf(gA0, gA0, fmaf(gA1, gA1, gA2 * gA2)));
    const float CtB = s2a * __builtin_amdgcn_exp2f(
        -c1 * fmaf(gB0, gB0, fmaf(gB1, gB1, gB2 * gB2)));

    const float4* Ac = A + c;
    float t0A = -INFINITY, t1A = -INFINITY, t0B = -INFINITY, t1B = -INFINITY;
    float SA0 = 0.f, SA1 = 0.f, SB0 = 0.f, SB1 = 0.f;

    if (s2a <= 1.0f) {
        // ---- fast path: 1 trans per (output,n) pair ----
        const float CtA2 = CtA * CtA, CtB2 = CtB * CtB;
        const float d1A = PC1 * CtA, d1B = PC1 * CtB;
        const float d2A = PC2 * CtA2, d2B = PC2 * CtB2;
        const float d3A = PC3 * CtA2 * CtA, d3B = PC3 * CtB2 * CtB;
        const float d4A = PC4 * CtA2 * CtA2, d4B = PC4 * CtB2 * CtB2;

        #pragma unroll 8
        for (int i = 0; i < 128; ++i) {
            const float4 a = Ac[i << 3];        // ONE read feeds BOTH outputs
            const float qA = fmaf(gA0, a.y, fmaf(gA1, a.z, fmaf(gA2, a.w, a.x)));
            const float qB = fmaf(gB0, a.y, fmaf(gB1, a.z, fmaf(gB2, a.w, a.x)));
            t1A = __builtin_amdgcn_fmed3f(t0A, t1A, qA); t0A = fmaxf(t0A, qA);
            t1B = __builtin_amdgcn_fmed3f(t0B, t1B, qB); t0B = fmaxf(t0B, qB);
            const float uA = __builtin_amdgcn_exp2f(qA);
            const float uB = __builtin_amdgcn_exp2f(qB);
            float QA = fmaf(d4A, uA, d3A);
            float QB = fmaf(d4B, uB, d3B);
            QA = fmaf(QA, uA, d2A); QB = fmaf(QB, uB, d2B);
            QA = fmaf(QA, uA, d1A); QB = fmaf(QB, uB, d1B);
            if (i & 1) { SA1 = fmaf(QA, uA, SA1); SB1 = fmaf(QB, uB, SB1); }
            else       { SA0 = fmaf(QA, uA, SA0); SB0 = fmaf(QB, uB, SB0); }
        }
    } else {
        // ---- general fallback: shifted 2-exp path (any s2a) ----
        const float ECA = LOG2E * CtA, ECB = LOG2E * CtB;
        const float Ls2 = LOG2E * s2a;
        #pragma unroll 8
        for (int i = 0; i < 128; ++i) {
            const float4 a = Ac[i << 3];
            const float qA = fmaf(gA0, a.y, fmaf(gA1, a.z, fmaf(gA2, a.w, a.x)));
            const float qB = fmaf(gB0, a.y, fmaf(gB1, a.z, fmaf(gB2, a.w, a.x)));
            t1A = __builtin_amdgcn_fmed3f(t0A, t1A, qA); t0A = fmaxf(t0A, qA);
            t1B = __builtin_amdgcn_fmed3f(t0B, t1B, qB); t0B = fmaxf(t0B, qB);
            const float wA = __builtin_amdgcn_exp2f(
                fmaf(ECA, __builtin_amdgcn_exp2f(qA), -Ls2));
            const float wB = __builtin_amdgcn_exp2f(
                fmaf(ECB, __builtin_amdgcn_exp2f(qB), -Ls2));
            if (i & 1) { SA1 += wA; SB1 += wB; }
            else       { SA0 += wA; SB0 += wB; }
        }
    }

    float SA = SA0 + SA1, SB = SB0 + SB1;
    omerge(t0A, t1A, SA);
    omerge(t0B, t1B, SB);

    if (c == 0) {
        float* ob = out + b * 32768;
        const float u0A = __builtin_amdgcn_exp2f(t0A);
        const float u1A = __builtin_amdgcn_exp2f(t1A);
        const float u0B = __builtin_amdgcn_exp2f(t0B);
        const float u1B = __builtin_amdgcn_exp2f(t1B);
        const float ECA = LOG2E * CtA, ECB = LOG2E * CtB;
        if (s2a <= 1.0f) {
            // exact exp2 numerator; poly only in S (d0 hoisted)
            const float numA = __builtin_amdgcn_exp2f(ECA * u0A)
                             - __builtin_amdgcn_exp2f(ECA * u1A);
            const float numB = __builtin_amdgcn_exp2f(ECB * u0B)
                             - __builtin_amdgcn_exp2f(ECB * u1B);
            ob[dhwA] = numA / fmaf(1024.f, PC0, SA);
            ob[dhwB] = numB / fmaf(1024.f, PC0, SB);
        } else {
            const float Ls2 = LOG2E * s2a;
            const float w0A = __builtin_amdgcn_exp2f(fmaf(ECA, u0A, -Ls2));
            const float w0B = __builtin_amdgcn_exp2f(fmaf(ECB, u0B, -Ls2));
            ob[dhwA] = w0A * (1.f - __builtin_amdgcn_exp2f(ECA * (u1A - u0A))) / SA;
            ob[dhwB] = w0B * (1.f - __builtin_amdgcn_exp2f(ECB * (u1B - u0B))) / SB;
        }
    }
}

extern "C" void kernel_launch(void* const* d_in, const int* in_sizes, int n_in,
                              void* d_out, int out_size, void* d_ws, size_t ws_size,
                              hipStream_t stream) {
    const float* xyz  = (const float*)d_in[0];
    const float* grid = (const float*)d_in[1];
    const float* s1   = (const float*)d_in[2];
    const float* s2   = (const float*)d_in[3];
    float* out        = (float*)d_out;
    hipLaunchKernelGGL(p2v_kernel, dim3(2048), dim3(256), 0, stream,
                       xyz, grid, s1, s2, out);
}

// Round 16
// 91.725 us; speedup vs baseline: 1.0508x; 1.0508x over previous
//
#include <hip/hip_runtime.h>
#include <math.h>

// P2V: out[b,dhw] = top2-margin over n of softmax_n( |s2| * exp(-|s1| * dist) )
// dist = |x|^2 + |g|^2 - 2 x.g
//
// Round 16: R8/R10/R13/R15 all pin at 45+-1.5us. Model that closes: VALUBusy
// counts main VALU (2 cyc) AND trans occupancy (16 cyc/exp): R13/R15 busy =
// 69.4 cyc per 2-output iter == 18*2 + 2*16 = 68 modeled -> we are AT the
// issue floor (~30us busy); dur-busy ~14us is ISSUE-IDLE. Suspect: per-iter
// ds_read->use chain (compiler sinks loads to uses - proven R7). Fix: 1-deep
// rotated prefetch (load iter i+1 before computing iter i), each load pinned
// with sched_barrier(0) so it cannot sink (R7 failure mode). lgkmcnt then
// lands after ~50cyc of independent compute. LDS +8 pad for last overreach.
//
// Math (= R10): q = -c1|x|^2 + 2c1(x.g), c1=log2e*|s1|; u = 2^q; v = Ct*u,
//   Ct = |s2|*2^(-c1|g|^2); top-2 of v == top-2 of q (monotone).
//   fast (s2a<=1): e^v ~ PC0 + u*Q(u) (deg-4 minimax, Ct^k folded into Q);
//     S_true = 1024*PC0 + sum(Q(u)u);  num = exact exp2: e^{v0} - e^{v1}.
//   general: S = sum 2^(EC*2^q - Ls2); out = 2^(EC*u0-Ls2)(1-2^(EC(u1-u0)))/S.

#define LOG2E 1.44269504088896340736f
// deg-4 minimax (Chebyshev) coeffs for e^x on [0,1], abs err <= 2.8e-5
#define PC0 1.0000247f
#define PC1 0.9987113f
#define PC2 0.5099871f
#define PC3 0.1399751f
#define PC4 0.0695533f

__device__ __forceinline__ void omerge(float& t0, float& t1, float& S) {
    #pragma unroll
    for (int m = 1; m <= 4; m <<= 1) {       // 8-lane butterfly
        const float o0 = __shfl_xor(t0, m);
        const float o1 = __shfl_xor(t1, m);
        const float oS = __shfl_xor(S, m);
        t1 = fmaxf(fminf(t0, o0), fmaxf(t1, o1));
        t0 = fmaxf(t0, o0);
        S += oS;
    }
}

// one 2-output evaluation of table entry `a` (fast path)
#define FASTBODY(a, sa, sb)                                                   \
    do {                                                                      \
        const float qA = fmaf(gA0, (a).y, fmaf(gA1, (a).z, fmaf(gA2, (a).w, (a).x))); \
        const float qB = fmaf(gB0, (a).y, fmaf(gB1, (a).z, fmaf(gB2, (a).w, (a).x))); \
        t1A = __builtin_amdgcn_fmed3f(t0A, t1A, qA); t0A = fmaxf(t0A, qA);    \
        t1B = __builtin_amdgcn_fmed3f(t0B, t1B, qB); t0B = fmaxf(t0B, qB);    \
        const float uA = __builtin_amdgcn_exp2f(qA);                          \
        const float uB = __builtin_amdgcn_exp2f(qB);                          \
        float QA = fmaf(d4A, uA, d3A);                                        \
        float QB = fmaf(d4B, uB, d3B);                                        \
        QA = fmaf(QA, uA, d2A); QB = fmaf(QB, uB, d2B);                       \
        QA = fmaf(QA, uA, d1A); QB = fmaf(QB, uB, d1B);                       \
        sa = fmaf(QA, uA, sa); sb = fmaf(QB, uB, sb);                         \
    } while (0)

// one 2-output evaluation (general fallback)
#define GENBODY(a, sa, sb)                                                    \
    do {                                                                      \
        const float qA = fmaf(gA0, (a).y, fmaf(gA1, (a).z, fmaf(gA2, (a).w, (a).x))); \
        const float qB = fmaf(gB0, (a).y, fmaf(gB1, (a).z, fmaf(gB2, (a).w, (a).x))); \
        t1A = __builtin_amdgcn_fmed3f(t0A, t1A, qA); t0A = fmaxf(t0A, qA);    \
        t1B = __builtin_amdgcn_fmed3f(t0B, t1B, qB); t0B = fmaxf(t0B, qB);    \
        sa += __builtin_amdgcn_exp2f(fmaf(ECA, __builtin_amdgcn_exp2f(qA), -Ls2)); \
        sb += __builtin_amdgcn_exp2f(fmaf(ECB, __builtin_amdgcn_exp2f(qB), -Ls2)); \
    } while (0)

__global__ __launch_bounds__(256, 8) void p2v_kernel(
    const float* __restrict__ xyz,   // (B=4, C=3, N=1024)
    const float* __restrict__ grid,  // (C=3, 32768)
    const float* __restrict__ s1,
    const float* __restrict__ s2,
    float* __restrict__ out)         // (B=4, 32768)
{
    __shared__ float4 A[1032];       // 1024 + 8 pad (prefetch overreach)

    const int tid  = threadIdx.x;
    const int b    = blockIdx.x >> 9;           // 512 blocks per b
    const int k    = blockIdx.x & 511;          // 64 outputs per block
    const int oct  = tid >> 3;                  // 32 octets
    const int c    = tid & 7;                   // n-chunk within octet
    const int dhwA = (k << 6) + oct;            // octet's output #1
    const int dhwB = dhwA + 32;                 // octet's output #2

    const float s1a = fabsf(s1[0]);
    const float s2a = fabsf(s2[0]);
    const float c1  = LOG2E * s1a;

    const float* xb = xyz + b * 3072;
    #pragma unroll
    for (int i = 0; i < 4; ++i) {
        const int n = tid + i * 256;
        const float x = xb[n], y = xb[1024 + n], z = xb[2048 + n];
        const float x2 = fmaf(x, x, fmaf(y, y, z * z));
        A[n] = make_float4(-c1 * x2, 2.f * c1 * x, 2.f * c1 * y, 2.f * c1 * z);
    }
    if (tid < 8) A[1024 + tid] = make_float4(0.f, 0.f, 0.f, 0.f);
    __syncthreads();

    const float gA0 = grid[dhwA], gA1 = grid[32768 + dhwA], gA2 = grid[65536 + dhwA];
    const float gB0 = grid[dhwB], gB1 = grid[32768 + dhwB], gB2 = grid[65536 + dhwB];
    const float CtA = s2a * __builtin_amdgcn_exp2f(
        -c1 * fmaf(gA0, gA0, fmaf(gA1, gA1, gA2 * gA2)));
    const float CtB = s2a * __builtin_amdgcn_exp2f(
        -c1 * fmaf(gB0, gB0, fmaf(gB1, gB1, gB2 * gB2)));

    const float4* Ac = A + c;
    float t0A = -INFINITY, t1A = -INFINITY, t0B = -INFINITY, t1B = -INFINITY;
    float SA0 = 0.f, SA1 = 0.f, SB0 = 0.f, SB1 = 0.f;

    if (s2a <= 1.0f) {
        // ---- fast path: 1 trans per (output,n); 1-deep rotated prefetch ----
        const float CtA2 = CtA * CtA, CtB2 = CtB * CtB;
        const float d1A = PC1 * CtA, d1B = PC1 * CtB;
        const float d2A = PC2 * CtA2, d2B = PC2 * CtB2;
        const float d3A = PC3 * CtA2 * CtA, d3B = PC3 * CtB2 * CtB;
        const float d4A = PC4 * CtA2 * CtA2, d4B = PC4 * CtB2 * CtB2;

        float4 a_cur = Ac[0];
        #pragma unroll 4
        for (int i = 0; i < 128; i += 2) {
            float4 a_nxt = Ac[(i + 1) << 3];
            __builtin_amdgcn_sched_barrier(0);   // pin: load stays above
            FASTBODY(a_cur, SA0, SB0);
            float4 a_n2 = Ac[(i + 2) << 3];      // pad read at i=126, unused
            __builtin_amdgcn_sched_barrier(0);
            FASTBODY(a_nxt, SA1, SB1);
            a_cur = a_n2;
        }
    } else {
        // ---- general fallback: shifted 2-exp path (any s2a) ----
        const float ECA = LOG2E * CtA, ECB = LOG2E * CtB;
        const float Ls2 = LOG2E * s2a;
        float4 a_cur = Ac[0];
        #pragma unroll 4
        for (int i = 0; i < 128; i += 2) {
            float4 a_nxt = Ac[(i + 1) << 3];
            __builtin_amdgcn_sched_barrier(0);
            GENBODY(a_cur, SA0, SB0);
            float4 a_n2 = Ac[(i + 2) << 3];
            __builtin_amdgcn_sched_barrier(0);
            GENBODY(a_nxt, SA1, SB1);
            a_cur = a_n2;
        }
    }

    float SA = SA0 + SA1, SB = SB0 + SB1;
    omerge(t0A, t1A, SA);
    omerge(t0B, t1B, SB);

    if (c == 0) {
        float* ob = out + b * 32768;
        const float u0A = __builtin_amdgcn_exp2f(t0A);
        const float u1A = __builtin_amdgcn_exp2f(t1A);
        const float u0B = __builtin_amdgcn_exp2f(t0B);
        const float u1B = __builtin_amdgcn_exp2f(t1B);
        const float ECA = LOG2E * CtA, ECB = LOG2E * CtB;
        if (s2a <= 1.0f) {
            // exact exp2 numerator; poly only in S (d0 hoisted)
            const float numA = __builtin_amdgcn_exp2f(ECA * u0A)
                             - __builtin_amdgcn_exp2f(ECA * u1A);
            const float numB = __builtin_amdgcn_exp2f(ECB * u0B)
                             - __builtin_amdgcn_exp2f(ECB * u1B);
            ob[dhwA] = numA / fmaf(1024.f, PC0, SA);
            ob[dhwB] = numB / fmaf(1024.f, PC0, SB);
        } else {
            const float Ls2 = LOG2E * s2a;
            const float w0A = __builtin_amdgcn_exp2f(fmaf(ECA, u0A, -Ls2));
            const float w0B = __builtin_amdgcn_exp2f(fmaf(ECB, u0B, -Ls2));
            ob[dhwA] = w0A * (1.f - __builtin_amdgcn_exp2f(ECA * (u1A - u0A))) / SA;
            ob[dhwB] = w0B * (1.f - __builtin_amdgcn_exp2f(ECB * (u1B - u0B))) / SB;
        }
    }
}

extern "C" void kernel_launch(void* const* d_in, const int* in_sizes, int n_in,
                              void* d_out, int out_size, void* d_ws, size_t ws_size,
                              hipStream_t stream) {
    const float* xyz  = (const float*)d_in[0];
    const float* grid = (const float*)d_in[1];
    const float* s1   = (const float*)d_in[2];
    const float* s2   = (const float*)d_in[3];
    float* out        = (float*)d_out;
    hipLaunchKernelGGL(p2v_kernel, dim3(2048), dim3(256), 0, stream,
                       xyz, grid, s1, s2, out);
}